// Round 18
// baseline (107.846 us; speedup 1.0000x reference)
//
#include <hip/hip_runtime.h>

typedef unsigned int u32;
typedef unsigned short u16;
typedef __attribute__((ext_vector_type(8))) short short8;
typedef __attribute__((ext_vector_type(4))) float f32x4;
typedef __attribute__((ext_vector_type(16))) float f32x16;

#define BB 8
#define KK 32
#define SS 4096
#define HH 2048
#define DD 1024
#define NSC 16       // s-chunks in pooling
#define SC_S 256     // s per chunk
#define CH (BB * KK * HH)  // partial-chunk stride (elements)

// ws layout (bytes)
#define OFF_W16  0ull           // bf16 [b][k][s]          : 2 MiB
#define OFF_WB   (2ull << 20)   // bf16 [d][h] (W^T)       : 4 MiB
#define OFF_PART (6ull << 20)   // bf16 [sc][b][k][h]      : 16 MiB
#define OFF_PQ   (23ull << 20)  // bf16 [row][h] pooled    : 1 MiB
#define OFF_PROJ (24ull << 20)  // f32 [row][d]            : 1 MiB
#define OFF_TICK (25ull << 20)  // u32 [16] row-group tickets

__device__ __forceinline__ u16 f2bf(float x) {
  u32 u = __float_as_uint(x);
  return (u16)((u + 0x7fffu + ((u >> 16) & 1u)) >> 16);  // RNE
}

// ---------------------------------------------------------------------------
// k_prep: dual-role (R14) + ticket zeroing each launch (replay-safe).
// Blocks [0,256): ownership -> bf16 weights w16[b][k][s].
// Blocks [256,768): W[h][d] -> WB[d][h] bf16 via LDS 64x64 transpose.
// ---------------------------------------------------------------------------
__global__ __launch_bounds__(256) void k_prep(const void* __restrict__ own,
                                              u16* __restrict__ w16,
                                              const float* __restrict__ W,
                                              u16* __restrict__ WB,
                                              u32* __restrict__ tick) {
  __shared__ float lds[64][65];
  const int t = threadIdx.x;

  if (blockIdx.x == 0 && t < 16) tick[t] = 0u;

  if (blockIdx.x < BB * KK) {
    // ---- weights role ----
    const int bk = blockIdx.x;  // b*32 + k
    __shared__ int s_mode;
    __shared__ int s_wcnt[4];
    __shared__ float s_inv;

    if (t < 64) {
      u32 w = ((const u32*)own)[t];
      bool wordok = (w <= 1u) || (w == 0x3f800000u);
      unsigned long long m = __ballot(wordok);
      if (t == 0) s_mode = (m == ~0ull) ? 1 : 0;  // 1: 4-byte elems, 0: bytes
    }
    __syncthreads();
    const int mode = s_mode;

    u32 bits = 0;  // bit j = own[b][k][t*16 + j]
    const size_t base = (size_t)bk * SS + (size_t)t * 16;
    if (mode == 0) {
      uint4 v = *(const uint4*)((const unsigned char*)own + base);
      u32 wa[4] = {v.x, v.y, v.z, v.w};
#pragma unroll
      for (int w = 0; w < 4; ++w)
#pragma unroll
        for (int j = 0; j < 4; ++j)
          if ((wa[w] >> (8 * j)) & 0xffu) bits |= 1u << (4 * w + j);
    } else {
      const u32* p = (const u32*)own + base;
#pragma unroll
      for (int j = 0; j < 16; ++j)
        if (p[j] != 0u) bits |= 1u << j;
    }

    int cnt = __popc(bits);
#pragma unroll
    for (int off = 1; off < 64; off <<= 1) cnt += __shfl_xor(cnt, off);
    if ((t & 63) == 0) s_wcnt[t >> 6] = cnt;
    __syncthreads();
    if (t == 0) {
      int tot = s_wcnt[0] + s_wcnt[1] + s_wcnt[2] + s_wcnt[3];
      s_inv = 1.0f / fmaxf((float)tot, 1.0f);
    }
    __syncthreads();
    const u32 hv = (u32)f2bf(s_inv);

    u32 outw[8];
#pragma unroll
    for (int j = 0; j < 8; ++j) {
      u32 lo = ((bits >> (2 * j)) & 1u) ? hv : 0u;
      u32 hi = ((bits >> (2 * j + 1)) & 1u) ? hv : 0u;
      outw[j] = lo | (hi << 16);
    }
    u32* wo = (u32*)w16 + (size_t)bk * (SS / 2) + (size_t)t * 8;
    uint4 o0 = {outw[0], outw[1], outw[2], outw[3]};
    uint4 o1 = {outw[4], outw[5], outw[6], outw[7]};
    ((uint4*)wo)[0] = o0;
    ((uint4*)wo)[1] = o1;
  } else {
    // ---- W-transpose role ----
    const int bidx = blockIdx.x - BB * KK;   // 0..511
    const int hb = (bidx & 31) * 64, db = (bidx >> 5) * 64;
    const int x = t & 63, y = t >> 6;
#pragma unroll
    for (int j = 0; j < 16; ++j) {
      int r = y + 4 * j;
      lds[r][x] = W[(size_t)(hb + r) * DD + db + x];
    }
    __syncthreads();
#pragma unroll
    for (int j = 0; j < 16; ++j) {
      int r = y + 4 * j;
      WB[(size_t)(db + r) * HH + hb + x] = f2bf(lds[x][r]);
    }
  }
}

// ---------------------------------------------------------------------------
// k_pool: VERIFIED R12 core — frozen. 1024 thr, 16 waves lockstep s-walk,
// 2 h-tiles/wave (4KB row-span, 16 loads in flight). Grid (2,16,8)=256
// blocks, 1 block/CU. At combined HBM+L3 roofline (R15 FETCH evidence).
// ---------------------------------------------------------------------------
__global__ __launch_bounds__(1024, 4) void k_pool(const float* __restrict__ plan,
                                                  const u16* __restrict__ w16,
                                                  u16* __restrict__ part) {
  const int hcb = blockIdx.x, sc = blockIdx.y, b = blockIdx.z;
  const int t = threadIdx.x, wv = t >> 6, l = t & 63;
  const int lc = l & 31, half = l >> 5;
  const int h0 = hcb * 1024 + wv * 64;
  const int s0 = sc * SC_S;

  const float* pb = plan + (size_t)b * SS * HH + h0 + lc;
  const u16* wa = w16 + (size_t)(b * KK + lc) * SS;

  f32x16 acc0, acc1;
#pragma unroll
  for (int r = 0; r < 16; ++r) { acc0[r] = 0.0f; acc1[r] = 0.0f; }

  for (int step = 0; step < SC_S / 16; ++step) {
    const int sb = s0 + step * 16 + half * 8;
    short8 a = *(const short8*)(wa + sb);
    const float* col = pb + (size_t)sb * HH;
    float f0[8], f1[8];
#pragma unroll
    for (int j = 0; j < 8; ++j) {
      f0[j] = col[(size_t)j * HH];
      f1[j] = col[(size_t)j * HH + 32];
    }
    short8 b0, b1;
#pragma unroll
    for (int j = 0; j < 8; ++j) {
      b0[j] = (short)f2bf(f0[j]);
      b1[j] = (short)f2bf(f1[j]);
    }
    acc0 = __builtin_amdgcn_mfma_f32_32x32x16_bf16(a, b0, acc0, 0, 0, 0);
    acc1 = __builtin_amdgcn_mfma_f32_32x32x16_bf16(a, b1, acc1, 0, 0, 0);
  }

  // C layout: col = lane&31, row = (reg&3) + 8*(reg>>2) + 4*(lane>>5)
  u16* po = part + ((size_t)sc * BB + b) * KK * HH + h0 + lc;
#pragma unroll
  for (int r = 0; r < 16; ++r) {
    int krow = (r & 3) + 8 * (r >> 2) + 4 * half;
    po[(size_t)krow * HH] = f2bf(acc0[r]);
    po[(size_t)krow * HH + 32] = f2bf(acc1[r]);
  }
}

// ---------------------------------------------------------------------------
// k_reduce: fold 16 bf16 s-chunk partials, pack pooled rows to bf16 (R14).
// ---------------------------------------------------------------------------
__global__ __launch_bounds__(256) void k_reduce(const u16* __restrict__ part,
                                                u32* __restrict__ pq) {
  const int i = blockIdx.x * 256 + threadIdx.x;  // over 256 rows * 1024 h-pairs
  const int row = i >> 10, hp = i & 1023;
  const u16* p = part + (size_t)row * HH + 2 * hp;
  float lo = 0.f, hi = 0.f;
#pragma unroll
  for (int sc = 0; sc < NSC; ++sc) {
    u32 v = *(const u32*)(p + (size_t)sc * CH);
    lo += __uint_as_float((v & 0xffffu) << 16);
    hi += __uint_as_float(v & 0xffff0000u);
  }
  pq[i] = (u32)f2bf(lo) | ((u32)f2bf(hi) << 16);
}

// ---------------------------------------------------------------------------
// k_projln: R14's 256-block MFMA projection + atomic-ticket LN epilogue.
// Each block writes its 16x64 tile, fences, bumps tick[rt]; the 16th
// arriver for a row-group LayerNorms its 16 rows (wave-local reduces only).
// Order-independent -> deterministic. Saves k_ln + one graph gap.
// ---------------------------------------------------------------------------
__global__ __launch_bounds__(256) void k_projln(const u16* __restrict__ pq,
                                                const u16* __restrict__ WB,
                                                const float* __restrict__ bias,
                                                const float* __restrict__ gamma,
                                                const float* __restrict__ beta,
                                                float* __restrict__ proj,
                                                u32* __restrict__ tick,
                                                float* __restrict__ out) {
  const int rt = blockIdx.x, ctg = blockIdx.y;
  const int t = threadIdx.x, w = t >> 6, l = t & 63;
  const int lr = l & 15, lg = l >> 4;
  const int r0 = rt * 16, c0 = (ctg * 4 + w) * 16;

  const u16* pa = pq + (size_t)(r0 + lr) * HH + lg * 8;
  const u16* pw = WB + (size_t)(c0 + lr) * HH + lg * 8;
  f32x4 acc = (f32x4){0.f, 0.f, 0.f, 0.f};
#pragma unroll 4
  for (int slab = 0; slab < 64; ++slab) {
    short8 a = *(const short8*)(pa + slab * 32);
    short8 bv = *(const short8*)(pw + slab * 32);
    acc = __builtin_amdgcn_mfma_f32_16x16x32_bf16(a, bv, acc, 0, 0, 0);
  }
  const float bs = bias[c0 + lr];
#pragma unroll
  for (int j = 0; j < 4; ++j)
    proj[(size_t)(r0 + lg * 4 + j) * DD + c0 + lr] = acc[j] + bs;

  // ---- ticket: last of the 16 col-blocks for this row-group runs LN ----
  __shared__ int s_last;
  __threadfence();  // release: tile visible before ticket
  if (t == 0) {
    u32 old = atomicAdd(&tick[rt], 1u);
    s_last = (old == 15u) ? 1 : 0;
  }
  __syncthreads();
  if (!s_last) return;
  __threadfence();  // acquire: all 16 tiles visible

  // LN tail: wave w handles rows rr = w, w+4, w+8, w+12 (wave-local only).
  for (int rr = w; rr < 16; rr += 4) {
    const int row = r0 + rr;
    const float* pr = proj + (size_t)row * DD;
    f32x4 x[4];
    float s1 = 0.f, s2 = 0.f;
#pragma unroll
    for (int q = 0; q < 4; ++q) {
      x[q] = ((const f32x4*)pr)[l + 64 * q];
#pragma unroll
      for (int e = 0; e < 4; ++e) {
        s1 += x[q][e];
        s2 += x[q][e] * x[q][e];
      }
    }
#pragma unroll
    for (int off = 1; off < 64; off <<= 1) {
      s1 += __shfl_xor(s1, off);
      s2 += __shfl_xor(s2, off);
    }
    const float mu = s1 * (1.0f / DD);
    const float var = s2 * (1.0f / DD) - mu * mu;
    const float rs = rsqrtf(var + 1e-5f);
    float* orow = out + (size_t)row * DD;
#pragma unroll
    for (int q = 0; q < 4; ++q) {
      f32x4 g = ((const f32x4*)gamma)[l + 64 * q];
      f32x4 be = ((const f32x4*)beta)[l + 64 * q];
      f32x4 o;
#pragma unroll
      for (int e = 0; e < 4; ++e)
        o[e] = (x[q][e] - mu) * rs * g[e] + be[e];
      ((f32x4*)orow)[l + 64 * q] = o;
    }
  }
}

// ---------------------------------------------------------------------------

extern "C" void kernel_launch(void* const* d_in, const int* in_sizes, int n_in,
                              void* d_out, int out_size, void* d_ws, size_t ws_size,
                              hipStream_t stream) {
  (void)in_sizes; (void)n_in; (void)out_size; (void)ws_size;
  const float* plan  = (const float*)d_in[0];
  const void*  own   = d_in[1];
  const float* W     = (const float*)d_in[2];
  const float* bias  = (const float*)d_in[3];
  const float* gamma = (const float*)d_in[4];
  const float* beta  = (const float*)d_in[5];
  float* out = (float*)d_out;
  char* ws = (char*)d_ws;

  u16*   w16  = (u16*)(ws + OFF_W16);
  u16*   WB   = (u16*)(ws + OFF_WB);
  u16*   part = (u16*)(ws + OFF_PART);
  u32*   pq   = (u32*)(ws + OFF_PQ);
  float* proj = (float*)(ws + OFF_PROJ);
  u32*   tick = (u32*)(ws + OFF_TICK);

  k_prep<<<dim3(BB * KK + (HH / 64) * (DD / 64)), dim3(256), 0, stream>>>(own, w16, W, WB, tick);
  k_pool<<<dim3(2, NSC, BB), dim3(1024), 0, stream>>>(plan, w16, part);
  k_reduce<<<dim3((BB * KK * (HH / 2)) / 256), dim3(256), 0, stream>>>(part, pq);
  k_projln<<<dim3(16, 16), dim3(256), 0, stream>>>((const u16*)pq, WB, bias, gamma, beta, proj, tick, out);
}

// Round 19
// 84.031 us; speedup vs baseline: 1.2834x; 1.2834x over previous
//
#include <hip/hip_runtime.h>

typedef unsigned int u32;
typedef unsigned short u16;
typedef __attribute__((ext_vector_type(8))) short short8;
typedef __attribute__((ext_vector_type(4))) float f32x4;
typedef __attribute__((ext_vector_type(16))) float f32x16;

#define BB 8
#define KK 32
#define SS 4096
#define HH 2048
#define DD 1024
#define NSC 16       // s-chunks in pooling
#define SC_S 256     // s per chunk
#define CH (BB * KK * HH)  // partial-chunk stride (elements)

// ws layout (bytes)
#define OFF_W16  0ull           // bf16 [b][k][s]          : 2 MiB
#define OFF_WB   (2ull << 20)   // bf16 [d][h] (W^T)       : 4 MiB
#define OFF_PART (6ull << 20)   // bf16 [sc][b][k][h]      : 16 MiB
#define OFF_PQ   (23ull << 20)  // bf16 [row][h] pooled    : 1 MiB
#define OFF_PROJ (24ull << 20)  // f32 [row][d]            : 1 MiB

__device__ __forceinline__ u16 f2bf(float x) {
  u32 u = __float_as_uint(x);
  return (u16)((u + 0x7fffu + ((u >> 16) & 1u)) >> 16);  // RNE
}

// ---------------------------------------------------------------------------
// k_prep: dual-role. Blocks [0, 256): ownership -> bf16 weights w16[b][k][s].
// Blocks [256, 768): W[h][d] -> WB[d][h] bf16 via LDS 64x64 transpose.
// ---------------------------------------------------------------------------
__global__ __launch_bounds__(256) void k_prep(const void* __restrict__ own,
                                              u16* __restrict__ w16,
                                              const float* __restrict__ W,
                                              u16* __restrict__ WB) {
  __shared__ float lds[64][65];
  const int t = threadIdx.x;

  if (blockIdx.x < BB * KK) {
    // ---- weights role ----
    const int bk = blockIdx.x;  // b*32 + k
    __shared__ int s_mode;
    __shared__ int s_wcnt[4];
    __shared__ float s_inv;

    if (t < 64) {
      u32 w = ((const u32*)own)[t];
      bool wordok = (w <= 1u) || (w == 0x3f800000u);
      unsigned long long m = __ballot(wordok);
      if (t == 0) s_mode = (m == ~0ull) ? 1 : 0;  // 1: 4-byte elems, 0: bytes
    }
    __syncthreads();
    const int mode = s_mode;

    u32 bits = 0;  // bit j = own[b][k][t*16 + j]
    const size_t base = (size_t)bk * SS + (size_t)t * 16;
    if (mode == 0) {
      uint4 v = *(const uint4*)((const unsigned char*)own + base);
      u32 wa[4] = {v.x, v.y, v.z, v.w};
#pragma unroll
      for (int w = 0; w < 4; ++w)
#pragma unroll
        for (int j = 0; j < 4; ++j)
          if ((wa[w] >> (8 * j)) & 0xffu) bits |= 1u << (4 * w + j);
    } else {
      const u32* p = (const u32*)own + base;
#pragma unroll
      for (int j = 0; j < 16; ++j)
        if (p[j] != 0u) bits |= 1u << j;
    }

    int cnt = __popc(bits);
#pragma unroll
    for (int off = 1; off < 64; off <<= 1) cnt += __shfl_xor(cnt, off);
    if ((t & 63) == 0) s_wcnt[t >> 6] = cnt;
    __syncthreads();
    if (t == 0) {
      int tot = s_wcnt[0] + s_wcnt[1] + s_wcnt[2] + s_wcnt[3];
      s_inv = 1.0f / fmaxf((float)tot, 1.0f);
    }
    __syncthreads();
    const u32 hv = (u32)f2bf(s_inv);

    u32 outw[8];
#pragma unroll
    for (int j = 0; j < 8; ++j) {
      u32 lo = ((bits >> (2 * j)) & 1u) ? hv : 0u;
      u32 hi = ((bits >> (2 * j + 1)) & 1u) ? hv : 0u;
      outw[j] = lo | (hi << 16);
    }
    u32* wo = (u32*)w16 + (size_t)bk * (SS / 2) + (size_t)t * 8;
    uint4 o0 = {outw[0], outw[1], outw[2], outw[3]};
    uint4 o1 = {outw[4], outw[5], outw[6], outw[7]};
    ((uint4*)wo)[0] = o0;
    ((uint4*)wo)[1] = o1;
  } else {
    // ---- W-transpose role ----
    const int bidx = blockIdx.x - BB * KK;   // 0..511
    const int hb = (bidx & 31) * 64, db = (bidx >> 5) * 64;
    const int x = t & 63, y = t >> 6;
#pragma unroll
    for (int j = 0; j < 16; ++j) {
      int r = y + 4 * j;
      lds[r][x] = W[(size_t)(hb + r) * DD + db + x];
    }
    __syncthreads();
#pragma unroll
    for (int j = 0; j < 16; ++j) {
      int r = y + 4 * j;
      WB[(size_t)(db + r) * HH + hb + x] = f2bf(lds[x][r]);
    }
  }
}

// ---------------------------------------------------------------------------
// k_pool: VERIFIED ~42-45us core (R12 accounting; R15 FETCH evidence shows
// ~6.4 TB/s effective = combined HBM+L3 roofline): 1024 thr, 16 waves
// lockstep s-walk, each wave owns TWO 32-h tiles (64 h, block row-span 4KB
// contiguous, 16 loads in flight per wave). Grid (2,16,8)=256 blocks,
// 1 block/CU, no barriers. bf16 partial epilogue. FROZEN.
// ---------------------------------------------------------------------------
__global__ __launch_bounds__(1024, 4) void k_pool(const float* __restrict__ plan,
                                                  const u16* __restrict__ w16,
                                                  u16* __restrict__ part) {
  const int hcb = blockIdx.x, sc = blockIdx.y, b = blockIdx.z;
  const int t = threadIdx.x, wv = t >> 6, l = t & 63;
  const int lc = l & 31, half = l >> 5;
  const int h0 = hcb * 1024 + wv * 64;
  const int s0 = sc * SC_S;

  const float* pb = plan + (size_t)b * SS * HH + h0 + lc;
  const u16* wa = w16 + (size_t)(b * KK + lc) * SS;

  f32x16 acc0, acc1;
#pragma unroll
  for (int r = 0; r < 16; ++r) { acc0[r] = 0.0f; acc1[r] = 0.0f; }

  for (int step = 0; step < SC_S / 16; ++step) {
    const int sb = s0 + step * 16 + half * 8;
    // A: lane lc = k-row, 8 contiguous s (shared by both h-tiles)
    short8 a = *(const short8*)(wa + sb);
    // B: lane lc = h-col; two 32-h tiles; 8 s-rows each (stride HH)
    const float* col = pb + (size_t)sb * HH;
    float f0[8], f1[8];
#pragma unroll
    for (int j = 0; j < 8; ++j) {
      f0[j] = col[(size_t)j * HH];
      f1[j] = col[(size_t)j * HH + 32];
    }
    short8 b0, b1;
#pragma unroll
    for (int j = 0; j < 8; ++j) {
      b0[j] = (short)f2bf(f0[j]);
      b1[j] = (short)f2bf(f1[j]);
    }
    acc0 = __builtin_amdgcn_mfma_f32_32x32x16_bf16(a, b0, acc0, 0, 0, 0);
    acc1 = __builtin_amdgcn_mfma_f32_32x32x16_bf16(a, b1, acc1, 0, 0, 0);
  }

  // C layout: col = lane&31, row = (reg&3) + 8*(reg>>2) + 4*(lane>>5)
  u16* po = part + ((size_t)sc * BB + b) * KK * HH + h0 + lc;
#pragma unroll
  for (int r = 0; r < 16; ++r) {
    int krow = (r & 3) + 8 * (r >> 2) + 4 * half;
    po[(size_t)krow * HH] = f2bf(acc0[r]);
    po[(size_t)krow * HH + 32] = f2bf(acc1[r]);
  }
}

// ---------------------------------------------------------------------------
// k_reduce: fold 16 bf16 s-chunk partials, pack pooled rows to bf16.
// 1024 blocks x 256 thr, coalesced. ~4us. Cannot be fused (R12: 16-block
// fusion = 560us; R17: atomic replacement = +8us net).
// ---------------------------------------------------------------------------
__global__ __launch_bounds__(256) void k_reduce(const u16* __restrict__ part,
                                                u32* __restrict__ pq) {
  const int i = blockIdx.x * 256 + threadIdx.x;  // over 256 rows * 1024 h-pairs
  const int row = i >> 10, hp = i & 1023;
  const u16* p = part + (size_t)row * HH + 2 * hp;
  float lo = 0.f, hi = 0.f;
#pragma unroll
  for (int sc = 0; sc < NSC; ++sc) {
    u32 v = *(const u32*)(p + (size_t)sc * CH);
    lo += __uint_as_float((v & 0xffffu) << 16);
    hi += __uint_as_float(v & 0xffff0000u);
  }
  pq[i] = (u32)f2bf(lo) | ((u32)f2bf(hi) << 16);
}

// ---------------------------------------------------------------------------
// k_proj: 256-block MFMA projection (~6us; never shrink the grid — R13).
// ---------------------------------------------------------------------------
__global__ __launch_bounds__(256) void k_proj(const u16* __restrict__ pq,
                                              const u16* __restrict__ WB,
                                              const float* __restrict__ bias,
                                              float* __restrict__ proj) {
  const int rt = blockIdx.x, ctg = blockIdx.y;
  const int t = threadIdx.x, w = t >> 6, l = t & 63;
  const int lr = l & 15, lg = l >> 4;
  const int r0 = rt * 16, c0 = (ctg * 4 + w) * 16;

  const u16* pa = pq + (size_t)(r0 + lr) * HH + lg * 8;
  const u16* pw = WB + (size_t)(c0 + lr) * HH + lg * 8;
  f32x4 acc = (f32x4){0.f, 0.f, 0.f, 0.f};
#pragma unroll 4
  for (int slab = 0; slab < 64; ++slab) {
    short8 a = *(const short8*)(pa + slab * 32);
    short8 bv = *(const short8*)(pw + slab * 32);
    acc = __builtin_amdgcn_mfma_f32_16x16x32_bf16(a, bv, acc, 0, 0, 0);
  }
  const float bs = bias[c0 + lr];
#pragma unroll
  for (int j = 0; j < 4; ++j)
    proj[(size_t)(r0 + lg * 4 + j) * DD + c0 + lr] = acc[j] + bs;
}

// ---------------------------------------------------------------------------
// k_ln: LayerNorm over D=1024, one block per row (exact ref math, f32).
// Fusing this into proj costs more than its gap (R18: ticket fences +24us).
// ---------------------------------------------------------------------------
__global__ __launch_bounds__(256) void k_ln(const float* __restrict__ proj,
                                            const float* __restrict__ gamma,
                                            const float* __restrict__ beta,
                                            float* __restrict__ out) {
  const int row = blockIdx.x, t = threadIdx.x;
  float4 v = ((const float4*)(proj + (size_t)row * DD))[t];
  float s1 = v.x + v.y + v.z + v.w;
  float s2 = v.x * v.x + v.y * v.y + v.z * v.z + v.w * v.w;
#pragma unroll
  for (int off = 1; off < 64; off <<= 1) {
    s1 += __shfl_xor(s1, off);
    s2 += __shfl_xor(s2, off);
  }
  __shared__ float a1[4], a2[4];
  if ((t & 63) == 0) { a1[t >> 6] = s1; a2[t >> 6] = s2; }
  __syncthreads();
  const float S1 = a1[0] + a1[1] + a1[2] + a1[3];
  const float S2 = a2[0] + a2[1] + a2[2] + a2[3];
  const float mu = S1 * (1.0f / DD);
  const float var = S2 * (1.0f / DD) - mu * mu;
  const float rs = rsqrtf(var + 1e-5f);
  float4 g = ((const float4*)gamma)[t];
  float4 be = ((const float4*)beta)[t];
  float4 o;
  o.x = (v.x - mu) * rs * g.x + be.x;
  o.y = (v.y - mu) * rs * g.y + be.y;
  o.z = (v.z - mu) * rs * g.z + be.z;
  o.w = (v.w - mu) * rs * g.w + be.w;
  ((float4*)(out + (size_t)row * DD))[t] = o;
}

// ---------------------------------------------------------------------------

extern "C" void kernel_launch(void* const* d_in, const int* in_sizes, int n_in,
                              void* d_out, int out_size, void* d_ws, size_t ws_size,
                              hipStream_t stream) {
  (void)in_sizes; (void)n_in; (void)out_size; (void)ws_size;
  const float* plan  = (const float*)d_in[0];
  const void*  own   = d_in[1];
  const float* W     = (const float*)d_in[2];
  const float* bias  = (const float*)d_in[3];
  const float* gamma = (const float*)d_in[4];
  const float* beta  = (const float*)d_in[5];
  float* out = (float*)d_out;
  char* ws = (char*)d_ws;

  u16*   w16  = (u16*)(ws + OFF_W16);
  u16*   WB   = (u16*)(ws + OFF_WB);
  u16*   part = (u16*)(ws + OFF_PART);
  u32*   pq   = (u32*)(ws + OFF_PQ);
  float* proj = (float*)(ws + OFF_PROJ);

  k_prep<<<dim3(BB * KK + (HH / 64) * (DD / 64)), dim3(256), 0, stream>>>(own, w16, W, WB);
  k_pool<<<dim3(2, NSC, BB), dim3(1024), 0, stream>>>(plan, w16, part);
  k_reduce<<<dim3((BB * KK * (HH / 2)) / 256), dim3(256), 0, stream>>>(part, pq);
  k_proj<<<dim3(16, 16), dim3(256), 0, stream>>>((const u16*)pq, WB, bias, proj);
  k_ln<<<dim3(BB * KK), dim3(256), 0, stream>>>(proj, gamma, beta, out);
}